// Round 14
// baseline (104.568 us; speedup 1.0000x reference)
//
#include <hip/hip_runtime.h>
#include <math.h>

#define NN 16384
#define HH 50
#define AA 16
#define LL 66
#define RELTOK 7

// ---- threefry2x32, JAX partitionable layout (verified green R6-R13) ----
__device__ __forceinline__ unsigned rotl32(unsigned x, int d){
  return (x << d) | (x >> (32 - d));
}
__device__ __forceinline__ void tfr(unsigned &x0, unsigned &x1, int r){
  x0 += x1; x1 = rotl32(x1, r); x1 ^= x0;
}
__device__ float gumbel_at(unsigned j){
  const unsigned k0 = 0u, k1 = 42u;
  const unsigned k2 = 0x1BD11BDAu ^ k0 ^ k1;
  unsigned x0 = 0u + k0;
  unsigned x1 = j  + k1;
  tfr(x0,x1,13); tfr(x0,x1,15); tfr(x0,x1,26); tfr(x0,x1,6);
  x0 += k1; x1 += k2 + 1u;
  tfr(x0,x1,17); tfr(x0,x1,29); tfr(x0,x1,16); tfr(x0,x1,24);
  x0 += k2; x1 += k0 + 2u;
  tfr(x0,x1,13); tfr(x0,x1,15); tfr(x0,x1,26); tfr(x0,x1,6);
  x0 += k0; x1 += k1 + 3u;
  tfr(x0,x1,17); tfr(x0,x1,29); tfr(x0,x1,16); tfr(x0,x1,24);
  x0 += k1; x1 += k2 + 4u;
  tfr(x0,x1,13); tfr(x0,x1,15); tfr(x0,x1,26); tfr(x0,x1,6);
  x0 += k2; x1 += k0 + 5u;
  const unsigned bits = x0 ^ x1;
  const float f = __uint_as_float((bits >> 9) | 0x3F800000u) - 1.0f;
  const float u = fmaxf(f + 1e-20f, 1e-20f);
  return -logf(-logf(u));
}

__global__ void size_sentinel(float* out, int code){
  if (threadIdx.x < 64) out[threadIdx.x] = 3000.f + (float)code;
}
__global__ void kcheck_kernel(const int* kPtr, float* out){
  if (kPtr[0] != 33 && threadIdx.x < 64)
    out[threadIdx.x] = 5000.f + (float)kPtr[0];
}

// ---------------- kernel 1: query = cat(self,target) @ W + b (unchanged, green) ----------------
__global__ __launch_bounds__(256) void query_kernel(
    const float* __restrict__ selfF, const float* __restrict__ targF,
    const float* __restrict__ W, const float* __restrict__ bvec,
    float* __restrict__ qout)
{
  __shared__ float lw[128*64];
  const int tid = threadIdx.x;
  for (int i = tid; i < 128*64; i += 256) lw[i] = W[i];
  __syncthreads();
  const int lane = tid & 63;
  const int wv = tid >> 6;
  const int base = blockIdx.x * 16 + wv * 4;
  for (int r = 0; r < 4; ++r){
    const int n = base + r;
    const float sv = selfF[(size_t)n*64 + lane];
    const float tv = targF[(size_t)n*64 + lane];
    float q = bvec[lane];
    #pragma unroll
    for (int k = 0; k < 64; ++k)
      q = fmaf(__shfl(sv, k), lw[k*64 + lane], q);
    #pragma unroll
    for (int k = 0; k < 64; ++k)
      q = fmaf(__shfl(tv, k), lw[(64+k)*64 + lane], q);
    qout[(size_t)n*64 + lane] = q;
  }
}

// ------- kernel 2: agg — 4-deep batched coalesced dist gather; all numerics frozen -------
__global__ __launch_bounds__(64) void node_agg(
    const int* __restrict__ histUV, const int* __restrict__ histR,
    const int* __restrict__ adj,
    const float* __restrict__ u2e, const float* __restrict__ v2e,
    const float* __restrict__ r2e, const float* __restrict__ relAtt,
    const float* __restrict__ qbuf,
    const int* __restrict__ kPtr, float* __restrict__ out)
{
  __shared__ float ras[128];
  __shared__ float lrel[8];
  __shared__ float qs[64];
  __shared__ float Gum[66];
  __shared__ int   Dlab[66];
  __shared__ float Dlog[66];
  __shared__ float Datt[66];
  __shared__ float Dw[66];
  __shared__ int   DnI[66];
  __shared__ float Cw[40];
  __shared__ int   Cn[40];

  const int lane = threadIdx.x;            // blockDim = 64 = one wave
  const int n = blockIdx.x;
  const int K = kPtr[0];

  ras[lane]      = relAtt[lane];
  ras[64 + lane] = relAtt[64 + lane];
  {
    const float rh = relAtt[64 + lane];
    #pragma unroll
    for (int r = 0; r < 8; ++r){
      float v = r2e[r*64 + lane] * rh;
      #pragma unroll
      for (int o = 1; o < 64; o <<= 1) v += __shfl_xor(v, o);
      if (lane == 0) lrel[r] = v;
    }
  }
  qs[lane] = qbuf[(size_t)n*64 + lane];

  // neighbor metadata in REGISTERS (lane owns row lane; lanes 0,1 own rows 64,65)
  int nbIdx;
  if (lane < HH){
    nbIdx = histUV[(size_t)n*HH + lane];
    Dlab[lane] = histR[(size_t)n*HH + lane];
  } else {
    nbIdx = adj[(size_t)n*AA + (lane - HH)];
    Dlab[lane] = RELTOK;
  }
  Gum[lane] = gumbel_at((unsigned)(n*LL + lane));
  int nbIdx2 = 0;
  if (lane < 2){
    nbIdx2 = adj[(size_t)n*AA + 14 + lane];
    Dlab[64 + lane] = RELTOK;
    Gum[64 + lane] = gumbel_at((unsigned)(n*LL + 64 + lane));
  }
  __syncthreads();

  // ---- dist + att, quarter-wave coalesced, 4-DEEP BATCHED loads ----
  // lane li handles dims [4li,4li+4); per-row fma chain + 16-lane butterfly == R13 (bit-identical)
  {
    const int g  = lane >> 4;     // group 0..3 -> row 4j+g
    const int li = lane & 15;     // position within group
    const float4 q4  = *reinterpret_cast<const float4*>(&qs[4*li]);
    const float4 ra4 = *reinterpret_cast<const float4*>(&ras[4*li]);
    #pragma unroll
    for (int jb = 0; jb < 17; jb += 4){
      float4 ev[4];
      int    rl[4];
      int    ridx[4];
      #pragma unroll
      for (int t = 0; t < 4; ++t){
        const int j = jb + t;
        const int l = 4*j + g;
        if (j < 17 && l < LL){
          const int idx = (l < 64) ? __shfl(nbIdx, l) : __shfl(nbIdx2, l - 64);
          const float* tbl = (l < HH) ? u2e : v2e;
          ev[t] = *(reinterpret_cast<const float4*>(tbl + (size_t)idx*64) + li);
          rl[t] = l; ridx[t] = idx;
        } else {
          rl[t] = -1;
        }
      }
      #pragma unroll
      for (int t = 0; t < 4; ++t){
        if (rl[t] >= 0){
          const int l = rl[t];
          const float4 e4 = ev[t];
          const float d0 = q4.x - e4.x;
          const float d1 = q4.y - e4.y;
          const float d2 = q4.z - e4.z;
          const float d3 = q4.w - e4.w;
          float s = fmaf(d0,d0, fmaf(d1,d1, fmaf(d2,d2, d3*d3)));
          float e = fmaf(e4.x,ra4.x, fmaf(e4.y,ra4.y, fmaf(e4.z,ra4.z, e4.w*ra4.w)));
          #pragma unroll
          for (int o = 1; o < 16; o <<= 1){
            s += __shfl_xor(s, o);
            e += __shfl_xor(e, o);
          }
          if (li == 0){
            Dlog[l] = Gum[l] - sqrtf(s);
            Datt[l] = e + lrel[Dlab[l]];
            DnI[l]  = ridx[t] | ((l < HH) ? 0 : (1 << 30));
          }
        }
      }
    }
  }
  __syncthreads();

  // ---- rank + select (UNCHANGED; stable tie-break == lax.top_k set) ----
  for (int rep = 0; rep < 2; ++rep){
    const int l = (rep == 0) ? lane : 64 + lane;
    if (l < LL && (rep == 0 || lane < 2)){
      const float v = Dlog[l];
      int r = 0;
      for (int m = 0; m < LL; ++m){
        const float lm = Dlog[m];
        r += (lm > v || (lm == v && m < l)) ? 1 : 0;
      }
      Dw[l] = (r < K) ? 1.f : 0.f;
    }
  }
  __syncthreads();

  // ---- wave-parallel softmax over selected set (UNCHANGED) ----
  {
    const float a0 = Datt[lane];
    const bool  s0 = Dw[lane] > 0.f;
    float a1 = 0.f; bool s1 = false;
    if (lane < 2){ a1 = Datt[64 + lane]; s1 = Dw[64 + lane] > 0.f; }
    float mx = s0 ? a0 : -INFINITY;
    if (s1) mx = fmaxf(mx, a1);
    #pragma unroll
    for (int o = 1; o < 64; o <<= 1) mx = fmaxf(mx, __shfl_xor(mx, o));
    const float e0 = s0 ? expf(a0 - mx) : 0.f;
    const float e1 = s1 ? expf(a1 - mx) : 0.f;
    float ss = e0 + e1;
    #pragma unroll
    for (int o = 1; o < 64; o <<= 1) ss += __shfl_xor(ss, o);
    const float inv = 1.0f / ss;
    Dw[lane] = e0 * inv;
    if (lane < 2) Dw[64 + lane] = e1 * inv;
  }
  __syncthreads();

  // ---- ballot-compact selected neighbors (UNCHANGED; order = l ascending) ----
  int M;
  {
    if (lane < 40){ Cw[lane] = 0.f; Cn[lane] = 0; }
    const float w = Dw[lane];
    const bool sel = (w > 0.f);
    const unsigned long long mask = __ballot(sel);
    const int pos = __popcll(mask & ((1ull << lane) - 1ull));
    if (sel){ Cw[pos] = w; Cn[pos] = DnI[lane]; }
    const int base = __popcll(mask);
    const bool s64 = Dw[64] > 0.f;
    const bool s65 = Dw[65] > 0.f;
    if (lane == 0 && s64){ Cw[base] = Dw[64]; Cn[base] = DnI[64]; }
    if (lane == 1 && s65){
      const int tp = base + (s64 ? 1 : 0);
      Cw[tp] = Dw[65]; Cn[tp] = DnI[65];
    }
    M = base + (s64 ? 1 : 0) + (s65 ? 1 : 0);
  }
  __syncthreads();

  // ---- weighted sum over compacted list (UNCHANGED; lane = dim, coalesced) ----
  float od = 0.f;
  if (M <= 36){
    #pragma unroll
    for (int i = 0; i < 36; ++i){
      const float w = Cw[i];
      const int enc = Cn[i];
      const float* tbl = (enc & (1 << 30)) ? v2e : u2e;
      od = fmaf(w, tbl[(size_t)(enc & 0x3FFFFFFF)*64 + lane], od);
    }
  } else {
    for (int i = 0; i < M; ++i){
      const float w = Cw[i];
      const int enc = Cn[i];
      const float* tbl = (enc & (1 << 30)) ? v2e : u2e;
      od = fmaf(w, tbl[(size_t)(enc & 0x3FFFFFFF)*64 + lane], od);
    }
  }
  out[(size_t)n*64 + lane] = od;
}

// ---------------- fallback: R6 fused dumb kernel (used only if ws too small) ----------------
__global__ __launch_bounds__(256) void node_agg_dumb(
    const float* __restrict__ selfF, const float* __restrict__ targF,
    const int* __restrict__ histUV, const int* __restrict__ histR,
    const int* __restrict__ adj,
    const float* __restrict__ u2e, const float* __restrict__ v2e,
    const float* __restrict__ r2e, const float* __restrict__ relAtt,
    const float* __restrict__ W, const float* __restrict__ bvec,
    const int* __restrict__ kPtr, float* __restrict__ out)
{
  __shared__ float lw[128*64];
  __shared__ float ras[128];
  __shared__ float lrel[8];
  __shared__ float cs[4][128];
  __shared__ float qs[4][64];
  __shared__ float Dlog[4][66];
  __shared__ float Datt[4][66];
  __shared__ float Dw[4][66];
  __shared__ int   DnI[4][66];

  const int tid = threadIdx.x;
  for (int i = tid; i < 128*64; i += 256) lw[i] = W[i];
  if (tid < 128) ras[tid] = relAtt[tid];
  if (tid < 64){
    const float rh = relAtt[64 + tid];
    #pragma unroll
    for (int r = 0; r < 8; ++r){
      float v = r2e[r*64 + tid] * rh;
      #pragma unroll
      for (int o = 1; o < 64; o <<= 1) v += __shfl_xor(v, o);
      if (tid == 0) lrel[r] = v;
    }
  }
  __syncthreads();

  const int lane = tid & 63;
  const int wv = tid >> 6;
  const int n = blockIdx.x * 4 + wv;
  const int K = kPtr[0];

  cs[wv][lane]      = selfF[(size_t)n*64 + lane];
  cs[wv][64 + lane] = targF[(size_t)n*64 + lane];
  __syncthreads();
  {
    float qd = bvec[lane];
    for (int k = 0; k < 128; ++k) qd = fmaf(cs[wv][k], lw[k*64 + lane], qd);
    qs[wv][lane] = qd;
  }
  __syncthreads();
  for (int rep = 0; rep < 2; ++rep){
    const int l = (rep == 0) ? lane : 64 + lane;
    if (l < LL && (rep == 0 || lane < 2)){
      int idx, lab;
      if (l < HH){ idx = histUV[(size_t)n*HH + l]; lab = histR[(size_t)n*HH + l]; }
      else       { idx = adj[(size_t)n*AA + (l - HH)]; lab = RELTOK; }
      const float* row = ((l < HH) ? u2e : v2e) + (size_t)idx*64;
      float s = 0.f, e = 0.f;
      for (int d = 0; d < 64; ++d){
        const float ev = row[d];
        const float df = qs[wv][d] - ev;
        s = fmaf(df, df, s);
        e = fmaf(ev, ras[d], e);
      }
      Dlog[wv][l] = gumbel_at((unsigned)(n*LL + l)) - sqrtf(s);
      Datt[wv][l] = e + lrel[lab];
      DnI[wv][l]  = idx | ((l < HH) ? 0 : (1 << 30));
    }
  }
  __syncthreads();
  for (int rep = 0; rep < 2; ++rep){
    const int l = (rep == 0) ? lane : 64 + lane;
    if (l < LL && (rep == 0 || lane < 2)){
      const float v = Dlog[wv][l];
      int r = 0;
      for (int m = 0; m < LL; ++m){
        const float lm = Dlog[wv][m];
        r += (lm > v || (lm == v && m < l)) ? 1 : 0;
      }
      Dw[wv][l] = (r < K) ? 1.f : 0.f;
    }
  }
  __syncthreads();
  if (lane == 0){
    float mx = -INFINITY;
    for (int l = 0; l < LL; ++l) if (Dw[wv][l] > 0.f) mx = fmaxf(mx, Datt[wv][l]);
    float ss = 0.f;
    for (int l = 0; l < LL; ++l){
      const float w = (Dw[wv][l] > 0.f) ? expf(Datt[wv][l] - mx) : 0.f;
      Dw[wv][l] = w; ss += w;
    }
    const float inv = 1.f / ss;
    for (int l = 0; l < LL; ++l) Dw[wv][l] *= inv;
  }
  __syncthreads();
  float od = 0.f;
  for (int l = 0; l < LL; ++l){
    const float w = Dw[wv][l];
    if (w != 0.f){
      const int enc = DnI[wv][l];
      const float* tbl = (enc & (1 << 30)) ? v2e : u2e;
      od = fmaf(w, tbl[(size_t)(enc & 0x3FFFFFFF)*64 + lane], od);
    }
  }
  out[(size_t)n*64 + lane] = od;
}

extern "C" void kernel_launch(void* const* d_in, const int* in_sizes, int n_in,
                              void* d_out, int out_size, void* d_ws, size_t ws_size,
                              hipStream_t stream)
{
  float* out = (float*)d_out;

  static const int exp_sizes[12] = {1048576, 1048576, 819200, 819200, 262144,
                                    6400000, 6400000, 512, 128, 8192, 64, 1};
  int bad = -1;
  if (n_in != 12) bad = 99;
  else {
    for (int i = 0; i < 12; ++i){
      if (in_sizes[i] != exp_sizes[i]){ bad = i; break; }
    }
  }
  if (bad >= 0){
    size_sentinel<<<1, 64, 0, stream>>>(out, bad);
    return;
  }

  const float* selfF  = (const float*)d_in[0];
  const float* targF  = (const float*)d_in[1];
  const int*   histUV = (const int*)d_in[2];
  const int*   histR  = (const int*)d_in[3];
  const int*   adj    = (const int*)d_in[4];
  const float* u2e    = (const float*)d_in[5];
  const float* v2e    = (const float*)d_in[6];
  const float* r2e    = (const float*)d_in[7];
  const float* relAtt = (const float*)d_in[8];
  const float* W      = (const float*)d_in[9];
  const float* bvec   = (const float*)d_in[10];
  const int*   kPtr   = (const int*)d_in[11];

  const size_t qbytes = (size_t)NN * 64 * sizeof(float);
  if (ws_size >= qbytes){
    float* qbuf = (float*)d_ws;
    query_kernel<<<NN/16, 256, 0, stream>>>(selfF, targF, W, bvec, qbuf);
    node_agg<<<NN, 64, 0, stream>>>(histUV, histR, adj, u2e, v2e, r2e,
                                    relAtt, qbuf, kPtr, out);
  } else {
    node_agg_dumb<<<NN/4, 256, 0, stream>>>(selfF, targF, histUV, histR, adj,
                                            u2e, v2e, r2e, relAtt, W, bvec,
                                            kPtr, out);
  }
  kcheck_kernel<<<1, 64, 0, stream>>>(kPtr, out);
}

// Round 15
// 101.603 us; speedup vs baseline: 1.0292x; 1.0292x over previous
//
#include <hip/hip_runtime.h>
#include <math.h>

#define NN 16384
#define HH 50
#define AA 16
#define LL 66
#define RELTOK 7

// ---- threefry2x32, JAX partitionable layout (verified green R6-R13) ----
__device__ __forceinline__ unsigned rotl32(unsigned x, int d){
  return (x << d) | (x >> (32 - d));
}
__device__ __forceinline__ void tfr(unsigned &x0, unsigned &x1, int r){
  x0 += x1; x1 = rotl32(x1, r); x1 ^= x0;
}
__device__ float gumbel_at(unsigned j){
  const unsigned k0 = 0u, k1 = 42u;
  const unsigned k2 = 0x1BD11BDAu ^ k0 ^ k1;
  unsigned x0 = 0u + k0;
  unsigned x1 = j  + k1;
  tfr(x0,x1,13); tfr(x0,x1,15); tfr(x0,x1,26); tfr(x0,x1,6);
  x0 += k1; x1 += k2 + 1u;
  tfr(x0,x1,17); tfr(x0,x1,29); tfr(x0,x1,16); tfr(x0,x1,24);
  x0 += k2; x1 += k0 + 2u;
  tfr(x0,x1,13); tfr(x0,x1,15); tfr(x0,x1,26); tfr(x0,x1,6);
  x0 += k0; x1 += k1 + 3u;
  tfr(x0,x1,17); tfr(x0,x1,29); tfr(x0,x1,16); tfr(x0,x1,24);
  x0 += k1; x1 += k2 + 4u;
  tfr(x0,x1,13); tfr(x0,x1,15); tfr(x0,x1,26); tfr(x0,x1,6);
  x0 += k2; x1 += k0 + 5u;
  const unsigned bits = x0 ^ x1;
  const float f = __uint_as_float((bits >> 9) | 0x3F800000u) - 1.0f;
  const float u = fmaxf(f + 1e-20f, 1e-20f);
  return -logf(-logf(u));
}

__global__ void size_sentinel(float* out, int code){
  if (threadIdx.x < 64) out[threadIdx.x] = 3000.f + (float)code;
}
__global__ void kcheck_kernel(const int* kPtr, float* out){
  if (kPtr[0] != 33 && threadIdx.x < 64)
    out[threadIdx.x] = 5000.f + (float)kPtr[0];
}

// ---------------- kernel 1: query = cat(self,target) @ W + b (unchanged, green) ----------------
__global__ __launch_bounds__(256) void query_kernel(
    const float* __restrict__ selfF, const float* __restrict__ targF,
    const float* __restrict__ W, const float* __restrict__ bvec,
    float* __restrict__ qout)
{
  __shared__ float lw[128*64];
  const int tid = threadIdx.x;
  for (int i = tid; i < 128*64; i += 256) lw[i] = W[i];
  __syncthreads();
  const int lane = tid & 63;
  const int wv = tid >> 6;
  const int base = blockIdx.x * 16 + wv * 4;
  for (int r = 0; r < 4; ++r){
    const int n = base + r;
    const float sv = selfF[(size_t)n*64 + lane];
    const float tv = targF[(size_t)n*64 + lane];
    float q = bvec[lane];
    #pragma unroll
    for (int k = 0; k < 64; ++k)
      q = fmaf(__shfl(sv, k), lw[k*64 + lane], q);
    #pragma unroll
    for (int k = 0; k < 64; ++k)
      q = fmaf(__shfl(tv, k), lw[(64+k)*64 + lane], q);
    qout[(size_t)n*64 + lane] = q;
  }
}

// ------- kernel 2: agg — COALESCED quarter-wave dist gather (R13 exact) -------
__global__ __launch_bounds__(64) void node_agg(
    const int* __restrict__ histUV, const int* __restrict__ histR,
    const int* __restrict__ adj,
    const float* __restrict__ u2e, const float* __restrict__ v2e,
    const float* __restrict__ r2e, const float* __restrict__ relAtt,
    const float* __restrict__ qbuf,
    const int* __restrict__ kPtr, float* __restrict__ out)
{
  __shared__ float ras[128];
  __shared__ float lrel[8];
  __shared__ float qs[64];
  __shared__ float Gum[66];
  __shared__ int   Didx[66];
  __shared__ int   Dlab[66];
  __shared__ float Dlog[66];
  __shared__ float Datt[66];
  __shared__ float Dw[66];
  __shared__ int   DnI[66];
  __shared__ float Cw[40];
  __shared__ int   Cn[40];

  const int lane = threadIdx.x;            // blockDim = 64 = one wave
  const int n = blockIdx.x;
  const int K = kPtr[0];

  ras[lane]      = relAtt[lane];
  ras[64 + lane] = relAtt[64 + lane];
  {
    const float rh = relAtt[64 + lane];
    #pragma unroll
    for (int r = 0; r < 8; ++r){
      float v = r2e[r*64 + lane] * rh;
      #pragma unroll
      for (int o = 1; o < 64; o <<= 1) v += __shfl_xor(v, o);
      if (lane == 0) lrel[r] = v;
    }
  }
  qs[lane] = qbuf[(size_t)n*64 + lane];

  // preload neighbor metadata + gumbels (bit-identical gumbel stream, lane l -> row l)
  if (lane < HH){
    Didx[lane] = histUV[(size_t)n*HH + lane];
    Dlab[lane] = histR[(size_t)n*HH + lane];
  } else {
    Didx[lane] = adj[(size_t)n*AA + (lane - HH)];
    Dlab[lane] = RELTOK;
  }
  Gum[lane] = gumbel_at((unsigned)(n*LL + lane));
  if (lane < 2){
    Didx[64 + lane] = adj[(size_t)n*AA + 14 + lane];
    Dlab[64 + lane] = RELTOK;
    Gum[64 + lane] = gumbel_at((unsigned)(n*LL + 64 + lane));
  }
  __syncthreads();

  // ---- dist + att, QUARTER-WAVE COALESCED: 16 lanes per row, 4 rows per iteration ----
  // lane li handles dims [4li,4li+4) (d-ascending within); 16-lane xor-butterfly combine.
  {
    const int g  = lane >> 4;     // group 0..3 -> row 4j+g
    const int li = lane & 15;     // position within group
    const float4 q4  = *reinterpret_cast<const float4*>(&qs[4*li]);
    const float4 ra4 = *reinterpret_cast<const float4*>(&ras[4*li]);
    #pragma unroll
    for (int j = 0; j < 17; ++j){
      const int l = 4*j + g;
      if (j < 16 || g < 2){       // l < 66
        const int idx = Didx[l];
        const float* tbl = (l < HH) ? u2e : v2e;
        const float4 ev = *(reinterpret_cast<const float4*>(tbl + (size_t)idx*64) + li);
        const float d0 = q4.x - ev.x;
        const float d1 = q4.y - ev.y;
        const float d2 = q4.z - ev.z;
        const float d3 = q4.w - ev.w;
        float s = fmaf(d0,d0, fmaf(d1,d1, fmaf(d2,d2, d3*d3)));
        float e = fmaf(ev.x,ra4.x, fmaf(ev.y,ra4.y, fmaf(ev.z,ra4.z, ev.w*ra4.w)));
        #pragma unroll
        for (int o = 1; o < 16; o <<= 1){
          s += __shfl_xor(s, o);
          e += __shfl_xor(e, o);
        }
        if (li == 0){
          Dlog[l] = Gum[l] - sqrtf(s);
          Datt[l] = e + lrel[Dlab[l]];
          DnI[l]  = idx | ((l < HH) ? 0 : (1 << 30));
        }
      }
    }
  }
  __syncthreads();

  // ---- rank + select (stable tie-break == lax.top_k set) ----
  for (int rep = 0; rep < 2; ++rep){
    const int l = (rep == 0) ? lane : 64 + lane;
    if (l < LL && (rep == 0 || lane < 2)){
      const float v = Dlog[l];
      int r = 0;
      for (int m = 0; m < LL; ++m){
        const float lm = Dlog[m];
        r += (lm > v || (lm == v && m < l)) ? 1 : 0;
      }
      Dw[l] = (r < K) ? 1.f : 0.f;
    }
  }
  __syncthreads();

  // ---- wave-parallel softmax over selected set ----
  {
    const float a0 = Datt[lane];
    const bool  s0 = Dw[lane] > 0.f;
    float a1 = 0.f; bool s1 = false;
    if (lane < 2){ a1 = Datt[64 + lane]; s1 = Dw[64 + lane] > 0.f; }
    float mx = s0 ? a0 : -INFINITY;
    if (s1) mx = fmaxf(mx, a1);
    #pragma unroll
    for (int o = 1; o < 64; o <<= 1) mx = fmaxf(mx, __shfl_xor(mx, o));
    const float e0 = s0 ? expf(a0 - mx) : 0.f;
    const float e1 = s1 ? expf(a1 - mx) : 0.f;
    float ss = e0 + e1;
    #pragma unroll
    for (int o = 1; o < 64; o <<= 1) ss += __shfl_xor(ss, o);
    const float inv = 1.0f / ss;
    Dw[lane] = e0 * inv;
    if (lane < 2) Dw[64 + lane] = e1 * inv;
  }
  __syncthreads();

  // ---- ballot-compact selected neighbors (order = l ascending) ----
  int M;
  {
    if (lane < 40){ Cw[lane] = 0.f; Cn[lane] = 0; }
    const float w = Dw[lane];
    const bool sel = (w > 0.f);
    const unsigned long long mask = __ballot(sel);
    const int pos = __popcll(mask & ((1ull << lane) - 1ull));
    if (sel){ Cw[pos] = w; Cn[pos] = DnI[lane]; }
    const int base = __popcll(mask);
    const bool s64 = Dw[64] > 0.f;
    const bool s65 = Dw[65] > 0.f;
    if (lane == 0 && s64){ Cw[base] = Dw[64]; Cn[base] = DnI[64]; }
    if (lane == 1 && s65){
      const int tp = base + (s64 ? 1 : 0);
      Cw[tp] = Dw[65]; Cn[tp] = DnI[65];
    }
    M = base + (s64 ? 1 : 0) + (s65 ? 1 : 0);
  }
  __syncthreads();

  // ---- weighted sum over compacted list (lane = dim, coalesced) ----
  float od = 0.f;
  if (M <= 36){
    #pragma unroll
    for (int i = 0; i < 36; ++i){
      const float w = Cw[i];
      const int enc = Cn[i];
      const float* tbl = (enc & (1 << 30)) ? v2e : u2e;
      od = fmaf(w, tbl[(size_t)(enc & 0x3FFFFFFF)*64 + lane], od);
    }
  } else {
    for (int i = 0; i < M; ++i){
      const float w = Cw[i];
      const int enc = Cn[i];
      const float* tbl = (enc & (1 << 30)) ? v2e : u2e;
      od = fmaf(w, tbl[(size_t)(enc & 0x3FFFFFFF)*64 + lane], od);
    }
  }
  out[(size_t)n*64 + lane] = od;
}

// ---------------- fallback: R6 fused dumb kernel (used only if ws too small) ----------------
__global__ __launch_bounds__(256) void node_agg_dumb(
    const float* __restrict__ selfF, const float* __restrict__ targF,
    const int* __restrict__ histUV, const int* __restrict__ histR,
    const int* __restrict__ adj,
    const float* __restrict__ u2e, const float* __restrict__ v2e,
    const float* __restrict__ r2e, const float* __restrict__ relAtt,
    const float* __restrict__ W, const float* __restrict__ bvec,
    const int* __restrict__ kPtr, float* __restrict__ out)
{
  __shared__ float lw[128*64];
  __shared__ float ras[128];
  __shared__ float lrel[8];
  __shared__ float cs[4][128];
  __shared__ float qs[4][64];
  __shared__ float Dlog[4][66];
  __shared__ float Datt[4][66];
  __shared__ float Dw[4][66];
  __shared__ int   DnI[4][66];

  const int tid = threadIdx.x;
  for (int i = tid; i < 128*64; i += 256) lw[i] = W[i];
  if (tid < 128) ras[tid] = relAtt[tid];
  if (tid < 64){
    const float rh = relAtt[64 + tid];
    #pragma unroll
    for (int r = 0; r < 8; ++r){
      float v = r2e[r*64 + tid] * rh;
      #pragma unroll
      for (int o = 1; o < 64; o <<= 1) v += __shfl_xor(v, o);
      if (tid == 0) lrel[r] = v;
    }
  }
  __syncthreads();

  const int lane = tid & 63;
  const int wv = tid >> 6;
  const int n = blockIdx.x * 4 + wv;
  const int K = kPtr[0];

  cs[wv][lane]      = selfF[(size_t)n*64 + lane];
  cs[wv][64 + lane] = targF[(size_t)n*64 + lane];
  __syncthreads();
  {
    float qd = bvec[lane];
    for (int k = 0; k < 128; ++k) qd = fmaf(cs[wv][k], lw[k*64 + lane], qd);
    qs[wv][lane] = qd;
  }
  __syncthreads();
  for (int rep = 0; rep < 2; ++rep){
    const int l = (rep == 0) ? lane : 64 + lane;
    if (l < LL && (rep == 0 || lane < 2)){
      int idx, lab;
      if (l < HH){ idx = histUV[(size_t)n*HH + l]; lab = histR[(size_t)n*HH + l]; }
      else       { idx = adj[(size_t)n*AA + (l - HH)]; lab = RELTOK; }
      const float* row = ((l < HH) ? u2e : v2e) + (size_t)idx*64;
      float s = 0.f, e = 0.f;
      for (int d = 0; d < 64; ++d){
        const float ev = row[d];
        const float df = qs[wv][d] - ev;
        s = fmaf(df, df, s);
        e = fmaf(ev, ras[d], e);
      }
      Dlog[wv][l] = gumbel_at((unsigned)(n*LL + l)) - sqrtf(s);
      Datt[wv][l] = e + lrel[lab];
      DnI[wv][l]  = idx | ((l < HH) ? 0 : (1 << 30));
    }
  }
  __syncthreads();
  for (int rep = 0; rep < 2; ++rep){
    const int l = (rep == 0) ? lane : 64 + lane;
    if (l < LL && (rep == 0 || lane < 2)){
      const float v = Dlog[wv][l];
      int r = 0;
      for (int m = 0; m < LL; ++m){
        const float lm = Dlog[wv][m];
        r += (lm > v || (lm == v && m < l)) ? 1 : 0;
      }
      Dw[wv][l] = (r < K) ? 1.f : 0.f;
    }
  }
  __syncthreads();
  if (lane == 0){
    float mx = -INFINITY;
    for (int l = 0; l < LL; ++l) if (Dw[wv][l] > 0.f) mx = fmaxf(mx, Datt[wv][l]);
    float ss = 0.f;
    for (int l = 0; l < LL; ++l){
      const float w = (Dw[wv][l] > 0.f) ? expf(Datt[wv][l] - mx) : 0.f;
      Dw[wv][l] = w; ss += w;
    }
    const float inv = 1.f / ss;
    for (int l = 0; l < LL; ++l) Dw[wv][l] *= inv;
  }
  __syncthreads();
  float od = 0.f;
  for (int l = 0; l < LL; ++l){
    const float w = Dw[wv][l];
    if (w != 0.f){
      const int enc = DnI[wv][l];
      const float* tbl = (enc & (1 << 30)) ? v2e : u2e;
      od = fmaf(w, tbl[(size_t)(enc & 0x3FFFFFFF)*64 + lane], od);
    }
  }
  out[(size_t)n*64 + lane] = od;
}

extern "C" void kernel_launch(void* const* d_in, const int* in_sizes, int n_in,
                              void* d_out, int out_size, void* d_ws, size_t ws_size,
                              hipStream_t stream)
{
  float* out = (float*)d_out;

  static const int exp_sizes[12] = {1048576, 1048576, 819200, 819200, 262144,
                                    6400000, 6400000, 512, 128, 8192, 64, 1};
  int bad = -1;
  if (n_in != 12) bad = 99;
  else {
    for (int i = 0; i < 12; ++i){
      if (in_sizes[i] != exp_sizes[i]){ bad = i; break; }
    }
  }
  if (bad >= 0){
    size_sentinel<<<1, 64, 0, stream>>>(out, bad);
    return;
  }

  const float* selfF  = (const float*)d_in[0];
  const float* targF  = (const float*)d_in[1];
  const int*   histUV = (const int*)d_in[2];
  const int*   histR  = (const int*)d_in[3];
  const int*   adj    = (const int*)d_in[4];
  const float* u2e    = (const float*)d_in[5];
  const float* v2e    = (const float*)d_in[6];
  const float* r2e    = (const float*)d_in[7];
  const float* relAtt = (const float*)d_in[8];
  const float* W      = (const float*)d_in[9];
  const float* bvec   = (const float*)d_in[10];
  const int*   kPtr   = (const int*)d_in[11];

  const size_t qbytes = (size_t)NN * 64 * sizeof(float);
  if (ws_size >= qbytes){
    float* qbuf = (float*)d_ws;
    query_kernel<<<NN/16, 256, 0, stream>>>(selfF, targF, W, bvec, qbuf);
    node_agg<<<NN, 64, 0, stream>>>(histUV, histR, adj, u2e, v2e, r2e,
                                    relAtt, qbuf, kPtr, out);
  } else {
    node_agg_dumb<<<NN/4, 256, 0, stream>>>(selfF, targF, histUV, histR, adj,
                                            u2e, v2e, r2e, relAtt, W, bvec,
                                            kPtr, out);
  }
  kcheck_kernel<<<1, 64, 0, stream>>>(kPtr, out);
}